// Round 1
// baseline (19.919 us; speedup 1.0000x reference)
//
#include <hip/hip_runtime.h>

// B-spline basis (ORDER=7, GRID=8, 16 knots) + einsum over H=8.
// One thread per row of 8 points. All arrays register-resident via full unroll.

__global__ __launch_bounds__(256) void bspline_kernel(
    const float* __restrict__ x,
    const float* __restrict__ knots,
    float* __restrict__ out,
    int nrows)
{
    int n = blockIdx.x * blockDim.x + threadIdx.x;
    if (n >= nrows) return;

    // Knot vector: 16 floats, uniform address -> scalar-cached loads.
    float U[16];
#pragma unroll
    for (int i = 0; i < 16; ++i) U[i] = knots[i];

    // s = (u - U0)/h with h = (U15-U0)/15; uniform knots => w1[i] = (s-i)/p.
    const float invh = 15.0f / (U[15] - U[0]);

    const float4* xp = reinterpret_cast<const float4*>(x) + (size_t)n * 2;
    float4 a = xp[0];
    float4 b = xp[1];
    float u[8] = {a.x, a.y, a.z, a.w, b.x, b.y, b.z, b.w};

    float acc[8];
#pragma unroll
    for (int k = 0; k < 8; ++k) acc[k] = 0.0f;

#pragma unroll
    for (int h = 0; h < 8; ++h) {
        const float uu = u[h];

        // Degree 0: N_i = 1 on [U[i], U[i+1])  (exact match to reference test)
        float Nb[15];
#pragma unroll
        for (int i = 0; i < 15; ++i)
            Nb[i] = (U[i] <= uu && uu < U[i + 1]) ? 1.0f : 0.0f;

        const float s = (uu - U[0]) * invh;

        // Levels p = 1..7:  Nb[i] = w[i]*Nb[i] + (1 - w[i+1])*Nb[i+1],
        // w[i] = (s - i)/p  (uniform-knot simplification of Cox-de Boor).
#pragma unroll
        for (int p = 1; p <= 7; ++p) {
            const float ip = 1.0f / (float)p;   // compile-time constant
            const int m = 15 - p;
            float w[16];
#pragma unroll
            for (int i = 0; i <= m; ++i) w[i] = (s - (float)i) * ip;
#pragma unroll
            for (int i = 0; i < m; ++i)
                Nb[i] = w[i] * Nb[i] + (1.0f - w[i + 1]) * Nb[i + 1];
        }

        // einsum: out[n,k] += u[n,h] * basis[n,h,k]
#pragma unroll
        for (int k = 0; k < 8; ++k)
            acc[k] = fmaf(uu, Nb[k], acc[k]);
    }

    float4* op = reinterpret_cast<float4*>(out) + (size_t)n * 2;
    op[0] = make_float4(acc[0], acc[1], acc[2], acc[3]);
    op[1] = make_float4(acc[4], acc[5], acc[6], acc[7]);
}

extern "C" void kernel_launch(void* const* d_in, const int* in_sizes, int n_in,
                              void* d_out, int out_size, void* d_ws, size_t ws_size,
                              hipStream_t stream) {
    const float* x     = (const float*)d_in[0];
    const float* knots = (const float*)d_in[1];
    float* out         = (float*)d_out;

    const int total = in_sizes[0];      // B*S*H = 1048576
    const int nrows = total / 8;        // 131072 rows of H=8

    const int block = 256;
    const int grid  = (nrows + block - 1) / block;
    bspline_kernel<<<grid, block, 0, stream>>>(x, knots, out, nrows);
}

// Round 2
// 12.660 us; speedup vs baseline: 1.5733x; 1.5733x over previous
//
#include <hip/hip_runtime.h>

// B-spline (ORDER=7, GRID=8, 16 uniform knots) + einsum over H=8.
// One thread per POINT (1M threads). Unnormalized Cox-de Boor on an 8-wide
// sliding window (only spans 7..14 are reachable for u in [0,1)); the 1/p
// normalizations fold into a single 1/5040. The einsum over H=8 is an 8-lane
// reduce-scatter butterfly so lane h writes out[n,h] coalesced.

__global__ __launch_bounds__(256) void bspline_kernel(
    const float* __restrict__ x,
    const float* __restrict__ knots,
    float* __restrict__ out,
    int npts)
{
    int t = blockIdx.x * blockDim.x + threadIdx.x;
    if (t >= npts) return;   // grid divides exactly; guard never splits a wave

    const float u = x[t];

    // s = (u - U0) * 15/(U15 - U0): uniform-knot parameter (U15-U0 = 2 -> 7.5)
    const float U0 = knots[0], U15 = knots[15];
    const float s = (u - U0) * (15.0f / (U15 - U0));

    // Degree 0: spans 7..14 only (u in [0,1) => U[7] <= u < U[15]).
    // Exact comparisons against the actual knot floats keep half-open
    // interval semantics identical to the reference.
    float g[7];
#pragma unroll
    for (int j = 0; j < 7; ++j)
        g[j] = (u >= knots[8 + j]) ? 1.0f : 0.0f;

    // A[r] = M_{7+r, 0} (indicator of span 7+r); g7 = 1, g15 = 0 implicit.
    float A[8];
    A[0] = 1.0f - g[0];
#pragma unroll
    for (int r = 1; r < 7; ++r) A[r] = g[r - 1] - g[r];
    A[7] = g[6];

    // d[i] = s - i (left weights, i in [1,13]); e[r] = (8+r) - s = -d[8+r]
    // (right weights, index independent of level).
    float d[14];
#pragma unroll
    for (int i = 1; i <= 13; ++i) d[i] = s - (float)i;
    float e[8];
#pragma unroll
    for (int r = 0; r < 8; ++r) e[r] = (float)(8 + r) - s;

    // Levels p = 1..7 on the sliding window A[r] = M_{7-p+r, p}:
    //   A_new[r] = d[7-p+r]*A_old[r-1] + e[r]*A_old[r]   (A_old[-1] = 0)
    // In-place with descending r. 15 VALU ops per level.
#pragma unroll
    for (int p = 1; p <= 7; ++p) {
#pragma unroll
        for (int r = 7; r >= 1; --r)
            A[r] = d[7 - p + r] * A[r - 1] + e[r] * A[r];
        A[0] = e[0] * A[0];
    }
    // Now A[k] = 5040 * N_{k,7}(u), k = 0..7.

    // v[k] = u * N_k = (u/5040) * A[k]
    const float up = u * (1.0f / 5040.0f);
    float v[8];
#pragma unroll
    for (int k = 0; k < 8; ++k) v[k] = up * A[k];

    // Reduce-scatter over the 8 lanes of this row (h = t & 7): after 3
    // butterfly steps lane h holds sum over h' of v_{h'}[h] = out[n,h].
    const int h = threadIdx.x & 7;
    const bool b2 = (h & 4) != 0, b1 = (h & 2) != 0, b0 = (h & 1) != 0;

    float a4[4];
#pragma unroll
    for (int r = 0; r < 4; ++r) {
        float send = b2 ? v[r] : v[r + 4];
        float keep = b2 ? v[r + 4] : v[r];
        a4[r] = keep + __shfl_xor(send, 4);
    }
    float a2[2];
#pragma unroll
    for (int r = 0; r < 2; ++r) {
        float send = b1 ? a4[r] : a4[r + 2];
        float keep = b1 ? a4[r + 2] : a4[r];
        a2[r] = keep + __shfl_xor(send, 2);
    }
    {
        float send = b0 ? a2[0] : a2[1];
        float keep = b0 ? a2[1] : a2[0];
        out[t] = keep + __shfl_xor(send, 1);
    }
}

extern "C" void kernel_launch(void* const* d_in, const int* in_sizes, int n_in,
                              void* d_out, int out_size, void* d_ws, size_t ws_size,
                              hipStream_t stream) {
    const float* x     = (const float*)d_in[0];
    const float* knots = (const float*)d_in[1];
    float* out         = (float*)d_out;

    const int npts = in_sizes[0];       // B*S*H = 1048576
    const int block = 256;
    const int grid  = (npts + block - 1) / block;
    bspline_kernel<<<grid, block, 0, stream>>>(x, knots, out, npts);
}

// Round 3
// 10.121 us; speedup vs baseline: 1.9680x; 1.2508x over previous
//
#include <hip/hip_runtime.h>

// B-spline (ORDER=7, GRID=8, 16 uniform knots) + einsum over H=8.
// One thread per POINT. Direct piecewise-polynomial evaluation of the
// cardinal B-spline B_7: N_k(u) = B_7(s-k), s=(u-U0)/h. With j=floor(s),
// t=s-j, the candidate values are p_m(t) = 5040*B_7(m+t), m=0..7 — eight
// degree-7 polynomials with compile-time integer coefficients (8 independent
// Horner chains). Output k = p_{j-k}(t) if 0<=j-k<=7 else 0, realized as a
// zero-fill register shift by sigma=j-7 (u in [0,1) => j in [7,14]).
// Einsum over H=8 via 8-lane reduce-scatter butterfly -> coalesced stores.

// p_m(t) = sum_d C[m][d] t^d ; verified: sum_m p_m(t) == 5040 (partition of
// unity), p_m(0) = {0,1,120,1191,2416,1191,120,1} = 5040*B_7(m).
__device__ __constant__ const float kC[8][8] = {
    {    0.f,     0.f,     0.f,     0.f,    0.f,    0.f,    0.f,   1.f},
    {    1.f,     7.f,    21.f,    35.f,   35.f,   21.f,    7.f,  -7.f},
    {  120.f,   392.f,   504.f,   280.f,    0.f,  -84.f,  -42.f,  21.f},
    { 1191.f,  1715.f,   315.f,  -665.f, -315.f,  105.f,  105.f, -35.f},
    { 2416.f,     0.f, -1680.f,     0.f,  560.f,    0.f, -140.f,  35.f},
    { 1191.f, -1715.f,   315.f,   665.f, -315.f, -105.f,  105.f, -21.f},
    {  120.f,  -392.f,   504.f,  -280.f,    0.f,   84.f,  -42.f,   7.f},
    {    1.f,    -7.f,    21.f,   -35.f,   35.f,  -21.f,    7.f,  -1.f},
};

__global__ __launch_bounds__(256) void bspline_kernel(
    const float* __restrict__ x,
    const float* __restrict__ knots,
    float* __restrict__ out,
    int npts)
{
    int t0 = blockIdx.x * blockDim.x + threadIdx.x;
    if (t0 >= npts) return;

    const float u = x[t0];

    const float U0 = knots[0], U15 = knots[15];
    const float s = (u - U0) * (15.0f / (U15 - U0));   // in [7.5, 15)

    const float fl = floorf(s);
    const float t  = s - fl;          // local parameter in [0,1)
    const int   ji = (int)fl;         // span index, 7..14
    const int   sg = ji - 7;          // shift amount, 0..7

    // Eight independent Horner chains: pv[m] = p_m(t) = 5040*B_7(m+t).
    float pv[8];
#pragma unroll
    for (int m = 0; m < 8; ++m) {
        float p = kC[m][7];
#pragma unroll
        for (int d = 6; d >= 0; --d) p = fmaf(p, t, kC[m][d]);
        pv[m] = p;
    }

    // Q[i] = pv[7-i]; output N_k*5040 = Q[k - sg] (zero-fill below).
    float Q[8];
#pragma unroll
    for (int i = 0; i < 8; ++i) Q[i] = pv[7 - i];

    const bool b4 = (sg & 4) != 0;
    const bool b2 = (sg & 2) != 0;
    const bool b1 = (sg & 1) != 0;
#pragma unroll
    for (int k = 7; k >= 0; --k) Q[k] = b4 ? (k >= 4 ? Q[k - 4] : 0.0f) : Q[k];
#pragma unroll
    for (int k = 7; k >= 0; --k) Q[k] = b2 ? (k >= 2 ? Q[k - 2] : 0.0f) : Q[k];
#pragma unroll
    for (int k = 7; k >= 0; --k) Q[k] = b1 ? (k >= 1 ? Q[k - 1] : 0.0f) : Q[k];

    // v[k] = u * N_k = (u/5040) * Q[k]
    const float up = u * (1.0f / 5040.0f);
    float v[8];
#pragma unroll
    for (int k = 0; k < 8; ++k) v[k] = up * Q[k];

    // Reduce-scatter over the 8 lanes of this row (h = t0 & 7): after 3
    // butterfly steps lane h holds sum over h' of v_{h'}[h] = out[n,h].
    const int h = threadIdx.x & 7;
    const bool c2 = (h & 4) != 0, c1 = (h & 2) != 0, c0 = (h & 1) != 0;

    float a4[4];
#pragma unroll
    for (int r = 0; r < 4; ++r) {
        float send = c2 ? v[r] : v[r + 4];
        float keep = c2 ? v[r + 4] : v[r];
        a4[r] = keep + __shfl_xor(send, 4);
    }
    float a2[2];
#pragma unroll
    for (int r = 0; r < 2; ++r) {
        float send = c1 ? a4[r] : a4[r + 2];
        float keep = c1 ? a4[r + 2] : a4[r];
        a2[r] = keep + __shfl_xor(send, 2);
    }
    {
        float send = c0 ? a2[0] : a2[1];
        float keep = c0 ? a2[1] : a2[0];
        out[t0] = keep + __shfl_xor(send, 1);
    }
}

extern "C" void kernel_launch(void* const* d_in, const int* in_sizes, int n_in,
                              void* d_out, int out_size, void* d_ws, size_t ws_size,
                              hipStream_t stream) {
    const float* x     = (const float*)d_in[0];
    const float* knots = (const float*)d_in[1];
    float* out         = (float*)d_out;

    const int npts = in_sizes[0];       // B*S*H = 1048576
    const int block = 256;
    const int grid  = (npts + block - 1) / block;
    bspline_kernel<<<grid, block, 0, stream>>>(x, knots, out, npts);
}

// Round 4
// 9.737 us; speedup vs baseline: 2.0457x; 1.0395x over previous
//
#include <hip/hip_runtime.h>

// B-spline (ORDER=7, GRID=8, 16 uniform knots) + einsum over H=8.
// Two points per thread (float2 load/store). Cardinal-spline pieces
// p_m(t) = 5040*B_7(m+t) evaluated via even/odd symmetric Horner about
// t=0.5 (p_m(t) = p_{7-m}(1-t)): S_m(q^2) + q*D_m(q^2), q = t-0.5.
// Output k = p_{j-k}(t), realized as zero-fill shift by sg=j-7.
// Row einsum: in-thread pair sum (points 2t,2t+1 share a row) + 2-stage
// 4-lane butterfly; lane a ends with out[row*8+2a..2a+1] = out2[tid].

static __device__ __forceinline__ void eval_point(
    float u, float U0, float sc, float v[8])
{
    const float s  = (u - U0) * sc;       // in [7.5, 15)
    const float fl = floorf(s);
    const float t  = s - fl;              // local parameter in [0,1)
    const int   sg = (int)fl - 7;         // shift, 0..7

    const float q  = t - 0.5f;
    const float q2 = q * q;

    // Even (S) and odd (D = odd/q) coefficient tables in powers of q^2 for
    // pairs (m, 7-m), m=0..3. All exact dyadic fp32. Verified:
    // 2*(sum_m S_m(0)) = 5040; p_4(0)=2416; p_1(1)=p_2(0)=120; p_7=(1-t)^7.
    constexpr float kS[4][4] = {
        {   0.0078125f,    0.65625f,    4.375f,   3.5f},
        {  17.0234375f,  154.21875f,   83.125f, -17.5f},
        { 473.8828125f,  793.40625f, -275.625f,  31.5f},
        {2029.0859375f, -948.28125f,  188.125f, -17.5f},
    };
    constexpr float kD[4][4] = {
        {   0.109375f,      2.1875f,     5.25f,   1.0f},
        {  78.859375f,    159.6875f,     5.25f,  -7.0f},
        {1074.171875f,     10.9375f,   -99.75f,  21.0f},
        {1422.421875f,   -846.5625f,   236.25f, -35.0f},
    };

    float pv[8];
#pragma unroll
    for (int m = 0; m < 4; ++m) {
        float S = fmaf(fmaf(fmaf(kS[m][3], q2, kS[m][2]), q2, kS[m][1]), q2, kS[m][0]);
        float D = fmaf(fmaf(fmaf(kD[m][3], q2, kD[m][2]), q2, kD[m][1]), q2, kD[m][0]);
        pv[m]     = fmaf( q, D, S);
        pv[7 - m] = fmaf(-q, D, S);
    }

    // Q[i] = pv[7-i]; 5040*N_k = Q[k - sg], zero-filled for k < sg.
    float Q[8];
#pragma unroll
    for (int i = 0; i < 8; ++i) Q[i] = pv[7 - i];

    const bool b4 = (sg & 4) != 0;
    const bool b2 = (sg & 2) != 0;
    const bool b1 = (sg & 1) != 0;
#pragma unroll
    for (int k = 7; k >= 0; --k) Q[k] = b4 ? (k >= 4 ? Q[k - 4] : 0.0f) : Q[k];
#pragma unroll
    for (int k = 7; k >= 0; --k) Q[k] = b2 ? (k >= 2 ? Q[k - 2] : 0.0f) : Q[k];
#pragma unroll
    for (int k = 7; k >= 0; --k) Q[k] = b1 ? (k >= 1 ? Q[k - 1] : 0.0f) : Q[k];

    // v[k] = u * N_k = (u/5040) * Q[k]
    const float up = u * (1.0f / 5040.0f);
#pragma unroll
    for (int k = 0; k < 8; ++k) v[k] = up * Q[k];
}

__global__ __launch_bounds__(256) void bspline_kernel(
    const float* __restrict__ x,
    const float* __restrict__ knots,
    float* __restrict__ out,
    int npairs)
{
    const int tid = blockIdx.x * blockDim.x + threadIdx.x;
    if (tid >= npairs) return;

    const float U0 = knots[0], U15 = knots[15];
    const float sc = 15.0f / (U15 - U0);

    const float2 uu = reinterpret_cast<const float2*>(x)[tid];

    float v0[8], v1[8];
    eval_point(uu.x, U0, sc, v0);
    eval_point(uu.y, U0, sc, v1);

    // Points 2*tid and 2*tid+1 belong to the same row -> sum in-register
    // (this replaces the xor-1 butterfly stage).
    float w[8];
#pragma unroll
    for (int k = 0; k < 8; ++k) w[k] = v0[k] + v1[k];

    // Remaining reduction across the row's 4 lanes (a = lane&3).
    // Lane a ends holding k in {2a, 2a+1} -> float2 store at out2[tid].
    const int a = threadIdx.x & 3;
    const bool hb2 = (a & 2) != 0;   // own ks have bit 4 set
    const bool hb1 = (a & 1) != 0;   // own ks have bit 2 set

    float s4[4];
#pragma unroll
    for (int r = 0; r < 4; ++r) {
        float send = hb2 ? w[r] : w[r + 4];
        float keep = hb2 ? w[r + 4] : w[r];
        s4[r] = keep + __shfl_xor(send, 2);
    }
    float s2[2];
#pragma unroll
    for (int r = 0; r < 2; ++r) {
        float send = hb1 ? s4[r] : s4[r + 2];
        float keep = hb1 ? s4[r + 2] : s4[r];
        s2[r] = keep + __shfl_xor(send, 1);
    }

    reinterpret_cast<float2*>(out)[tid] = make_float2(s2[0], s2[1]);
}

extern "C" void kernel_launch(void* const* d_in, const int* in_sizes, int n_in,
                              void* d_out, int out_size, void* d_ws, size_t ws_size,
                              hipStream_t stream) {
    const float* x     = (const float*)d_in[0];
    const float* knots = (const float*)d_in[1];
    float* out         = (float*)d_out;

    const int npts   = in_sizes[0];     // B*S*H = 1048576
    const int npairs = npts / 2;        // 524288

    const int block = 256;
    const int grid  = (npairs + block - 1) / block;
    bspline_kernel<<<grid, block, 0, stream>>>(x, knots, out, npairs);
}